// Round 5
// baseline (509.417 us; speedup 1.0000x reference)
//
#include <hip/hip_runtime.h>
#include <math.h>

typedef __bf16 bf16;
typedef __attribute__((ext_vector_type(8))) __bf16 bf16x8;
typedef __attribute__((ext_vector_type(4))) __bf16 bf16x4;
typedef __attribute__((ext_vector_type(4))) float floatx4;

#define MFMA(a, b, c) __builtin_amdgcn_mfma_f32_16x16x32_bf16((a), (b), (c), 0, 0, 0)

__device__ __forceinline__ void async_load16(const bf16* g, bf16* l) {
    __builtin_amdgcn_global_load_lds((const __attribute__((address_space(1))) void*)(g),
                                     (__attribute__((address_space(3))) void*)(l), 16, 0, 0);
}

// ---------------------------------------------------------------------------
// fp32 -> bf16 cast of all 4 weight matrices in one launch.
// ---------------------------------------------------------------------------
__global__ __launch_bounds__(256) void cast4_kernel(const float* __restrict__ a0,
                                                    const float* __restrict__ a1,
                                                    const float* __restrict__ a2,
                                                    const float* __restrict__ a3,
                                                    bf16* __restrict__ o0,
                                                    bf16* __restrict__ o1,
                                                    bf16* __restrict__ o2,
                                                    bf16* __restrict__ o3) {
    long i = (long)blockIdx.x * 256 + threadIdx.x;  // 8-elem units
    const float* in;
    bf16* out;
    long off;
    if (i < 393216) { in = a0; out = o0; off = i; }
    else if (i < 524288) { in = a1; out = o1; off = i - 393216; }
    else if (i < 1048576) { in = a2; out = o2; off = i - 524288; }
    else { in = a3; out = o3; off = i - 1048576; }
    const float4 a = ((const float4*)in)[2 * off];
    const float4 b = ((const float4*)in)[2 * off + 1];
    bf16x8 o;
    o[0] = (bf16)a.x; o[1] = (bf16)a.y; o[2] = (bf16)a.z; o[3] = (bf16)a.w;
    o[4] = (bf16)b.x; o[5] = (bf16)b.y; o[6] = (bf16)b.z; o[7] = (bf16)b.w;
    *(bf16x8*)(out + off * 8) = o;
}

// ---------------------------------------------------------------------------
// LayerNorm over 1024 cols, fp32 in -> bf16 out. One block (256 thr) per row.
// ---------------------------------------------------------------------------
__global__ __launch_bounds__(256) void ln_kernel(const float* __restrict__ x,
                                                 const float* __restrict__ g,
                                                 const float* __restrict__ b,
                                                 bf16* __restrict__ out) {
    const int row = blockIdx.x;
    const int tid = threadIdx.x;
    const float4 v = ((const float4*)(x + (long)row * 1024))[tid];
    float s  = v.x + v.y + v.z + v.w;
    float s2 = v.x * v.x + v.y * v.y + v.z * v.z + v.w * v.w;
#pragma unroll
    for (int off = 32; off > 0; off >>= 1) {
        s  += __shfl_xor(s, off, 64);
        s2 += __shfl_xor(s2, off, 64);
    }
    __shared__ float red[8];
    const int wave = tid >> 6, lane = tid & 63;
    if (lane == 0) { red[wave] = s; red[wave + 4] = s2; }
    __syncthreads();
    const float ts  = red[0] + red[1] + red[2] + red[3];
    const float ts2 = red[4] + red[5] + red[6] + red[7];
    const float mu   = ts * (1.0f / 1024.0f);
    const float rstd = rsqrtf(ts2 * (1.0f / 1024.0f) - mu * mu + 1e-5f);
    const float4 gg = ((const float4*)g)[tid];
    const float4 bb = ((const float4*)b)[tid];
    bf16x4 o;
    o[0] = (bf16)((v.x - mu) * rstd * gg.x + bb.x);
    o[1] = (bf16)((v.y - mu) * rstd * gg.y + bb.y);
    o[2] = (bf16)((v.z - mu) * rstd * gg.z + bb.z);
    o[3] = (bf16)((v.w - mu) * rstd * gg.w + bb.w);
    *(bf16x4*)(out + (long)row * 1024 + tid * 4) = o;
}

// ---------------------------------------------------------------------------
// bf16 NT GEMM: C[m,n] = sum_k A[m,k] * B[n,k]  (A:[M,K], B:[N,K] row-major)
// 128x128 tile, BK=64, global_load_lds(16B) staging, XOR chunk swizzle,
// 16x16x32 bf16 MFMA.
// XCD swizzle: flat block id -> xcd = id&7 owns a contiguous band of N-tiles
// (gridDim.x % 8 == 0 for all our shapes) so the B-weight band (<=1 MB) stays
// L2-resident for the whole launch and A-tiles are reused temporally per XCD.
// EPI: 0 = bf16 out; 1 = +bias+resid -> fp32; 2 = +bias,GELU -> bf16;
//      3 = qkv: Q/K bf16 out, V cols (n>=2048) stored TRANSPOSED into vtout.
// ---------------------------------------------------------------------------
template <int EPI>
__global__ __launch_bounds__(256, 3)
void gemm_bt(const bf16* __restrict__ A, const bf16* __restrict__ B,
             const float* __restrict__ bias, const float* __restrict__ resid,
             void* __restrict__ Cout, bf16* __restrict__ vtout, int M, int N, int K) {
    __shared__ __align__(16) bf16 sA[128 * 64];
    __shared__ __align__(16) bf16 sB[128 * 64];
    const int tid  = threadIdx.x;
    const int lane = tid & 63;
    const int wave = tid >> 6;
    const int wm = (wave >> 1) << 6;
    const int wn = (wave & 1) << 6;
    const int c15 = lane & 15;
    const int kq  = lane >> 4;
    const int c7  = lane & 7;

    // XCD-aware tile assignment
    const int flat  = blockIdx.y * gridDim.x + blockIdx.x;
    const int xcd   = flat & 7;
    const int local = flat >> 3;
    const int ntX   = gridDim.x >> 3;           // N-tiles per XCD (3/4/1)
    const int mtile = local / ntX;
    const int ntile = xcd * ntX + (local - mtile * ntX);
    const long tileM = (long)mtile * 128;
    const long tileN = (long)ntile * 128;

    floatx4 acc[4][4] = {};

    const int srow = tid >> 3;
    const int scol = ((tid & 7) ^ (srow & 7)) * 8;
    const bf16* Abase = A + (tileM + srow) * (long)K + scol;
    const bf16* Bbase = B + (tileN + srow) * (long)K + scol;
    bf16* sAw = sA + tid * 8;
    bf16* sBw = sB + tid * 8;

    for (int k0 = 0; k0 < K; k0 += 64) {
        __syncthreads();
#pragma unroll
        for (int it = 0; it < 4; ++it) {
            async_load16(Abase + (long)it * 32 * K + k0, sAw + it * 2048);
            async_load16(Bbase + (long)it * 32 * K + k0, sBw + it * 2048);
        }
        __syncthreads();
#pragma unroll
        for (int kk = 0; kk < 2; ++kk) {
            bf16x8 a[4], b[4];
#pragma unroll
            for (int i = 0; i < 4; ++i) {
                const int ch = ((kk << 2) + kq) ^ c7;
                a[i] = *(const bf16x8*)(sA + (wm + i * 16 + c15) * 64 + ch * 8);
                b[i] = *(const bf16x8*)(sB + (wn + i * 16 + c15) * 64 + ch * 8);
            }
#pragma unroll
            for (int i = 0; i < 4; ++i)
#pragma unroll
                for (int j = 0; j < 4; ++j)
                    acc[i][j] = MFMA(a[i], b[j], acc[i][j]);
        }
    }

#pragma unroll
    for (int i = 0; i < 4; ++i)
#pragma unroll
        for (int j = 0; j < 4; ++j) {
            if (EPI == 3 && tileN >= 2048) {
                // V: transposed store. Lane holds 4 consecutive tokens, fixed col.
                const long gnv  = tileN - 2048 + wn + j * 16 + c15;   // b-local V col
                const long tokb = tileM + wm + i * 16 + kq * 4;       // global token base
                const long row  = ((tokb >> 11) << 10) + gnv;         // b*1024 + gnv
                bf16x4 ov;
#pragma unroll
                for (int r = 0; r < 4; ++r) ov[r] = (bf16)acc[i][j][r];
                *(bf16x4*)(vtout + row * 2048 + (tokb & 2047)) = ov;
            } else {
#pragma unroll
                for (int r = 0; r < 4; ++r) {
                    const long gm = tileM + wm + i * 16 + kq * 4 + r;
                    const long gn = tileN + wn + j * 16 + c15;
                    const float v = acc[i][j][r];
                    if (EPI == 0 || EPI == 3) {
                        ((bf16*)Cout)[gm * N + gn] = (bf16)v;
                    } else if (EPI == 1) {
                        ((float*)Cout)[gm * N + gn] = v + bias[gn] + resid[gm * N + gn];
                    } else {
                        const float t = v + bias[gn];
                        ((bf16*)Cout)[gm * N + gn] =
                            (bf16)(0.5f * t * (1.0f + erff(t * 0.70710678118654752f)));
                    }
                }
            }
        }
}

// ---------------------------------------------------------------------------
// Flash attention, S^T/O^T formulation, NO online max (scores bounded; see R3).
// R5: double-buffered sK/sV with ONE barrier per kv-tile — tile i+1's
// global_load_lds issued right after barrier i, so its latency hides behind
// compute of tile i; the vmcnt(0) drain at barrier i+1 sees it near-complete.
// Block = 256 thr (4 waves), 128 q rows per block (wave: 32 q = 2 q-tiles).
// S^T = K.Q^T; scale*log2(e) folded into Q; p = exp2(S). O^T = V^T.P^T.
// Grid: x = bh (64) -> same-bh blocks land on same XCD; K/V L2-resident.
// ---------------------------------------------------------------------------
__global__ __launch_bounds__(256, 3)
void attn_kernel(const bf16* __restrict__ qkv, const bf16* __restrict__ vt,
                 bf16* __restrict__ o) {
    __shared__ __align__(16) bf16 sK[2][64 * 64];
    __shared__ __align__(16) bf16 sV[2][64 * 64];       // vt tile: [d][kv]
    __shared__ __align__(16) bf16 sP[8][16 * 72];       // [wave*2+t][q][kv(+pad)]
    const int bh = blockIdx.x, b = bh >> 4, h = bh & 15;
    const int q0 = blockIdx.y * 128;
    const int tid = threadIdx.x, lane = tid & 63, wave = tid >> 6;
    const int c15 = lane & 15, kq = lane >> 4, c7 = lane & 7;

    // Q fragments (B-operand layout: n=c15, k=kq*8..+8), pre-scaled by log2(e)/8
    bf16x8 qf[2][2];
#pragma unroll
    for (int t = 0; t < 2; ++t) {
        const bf16* qrow =
            qkv + ((long)(b * 2048 + q0 + wave * 32 + t * 16 + c15)) * 3072 + h * 64;
#pragma unroll
        for (int kk = 0; kk < 2; ++kk) {
            const bf16x8 raw = *(const bf16x8*)(qrow + kk * 32 + kq * 8);
            bf16x8 sc;
#pragma unroll
            for (int e = 0; e < 8; ++e) sc[e] = (bf16)((float)raw[e] * 0.18033688f);
            qf[t][kk] = sc;
        }
    }

    floatx4 oacc[2][4] = {};
    float l_s[2] = {0.f, 0.f};

    const bf16* kbase = qkv + ((long)b * 2048) * 3072 + 1024 + h * 64;
    const bf16* vbase = vt + (long)bh * 64 * 2048;

    const int srow = tid >> 3;
    const int scol = ((tid & 7) ^ (srow & 7)) * 8;
    bf16* sP0 = sP[wave * 2];
    bf16* sP1 = sP[wave * 2 + 1];

#define ATTN_ISSUE(kv, buf)                                                              \
    {                                                                                    \
        bf16* sKw = sK[buf] + tid * 8;                                                   \
        bf16* sVw = sV[buf] + tid * 8;                                                   \
        _Pragma("unroll") for (int it = 0; it < 2; ++it) {                               \
            async_load16(kbase + (long)((kv) + it * 32 + srow) * 3072 + scol,            \
                         sKw + it * 2048);                                               \
            async_load16(vbase + (long)(it * 32 + srow) * 2048 + (kv) + scol,            \
                         sVw + it * 2048);                                               \
        }                                                                                \
    }

#define ATTN_COMPUTE(buf)                                                                \
    {                                                                                    \
        const bf16* sKc = sK[buf];                                                       \
        const bf16* sVc = sV[buf];                                                       \
        floatx4 s0[4], s1[4];                                                            \
        _Pragma("unroll") for (int j = 0; j < 4; ++j) {                                  \
            const bf16x8 k0 =                                                            \
                *(const bf16x8*)(sKc + (j * 16 + c15) * 64 + ((kq ^ c7) * 8));           \
            const bf16x8 k1 =                                                            \
                *(const bf16x8*)(sKc + (j * 16 + c15) * 64 + (((4 | kq) ^ c7) * 8));     \
            floatx4 a0 = {0.f, 0.f, 0.f, 0.f}, a1 = {0.f, 0.f, 0.f, 0.f};                \
            a0 = MFMA(k0, qf[0][0], a0);                                                 \
            a0 = MFMA(k1, qf[0][1], a0);                                                 \
            a1 = MFMA(k0, qf[1][0], a1);                                                 \
            a1 = MFMA(k1, qf[1][1], a1);                                                 \
            s0[j] = a0;                                                                  \
            s1[j] = a1;                                                                  \
        }                                                                                \
        _Pragma("unroll") for (int t = 0; t < 2; ++t) {                                  \
            floatx4* s = (t == 0) ? s0 : s1;                                             \
            bf16* sPt = (t == 0) ? sP0 : sP1;                                            \
            float rs = 0.f;                                                              \
            _Pragma("unroll") for (int j = 0; j < 4; ++j) {                               \
                const float p0 = __builtin_amdgcn_exp2f(s[j][0]);                        \
                const float p1 = __builtin_amdgcn_exp2f(s[j][1]);                        \
                const float p2 = __builtin_amdgcn_exp2f(s[j][2]);                        \
                const float p3 = __builtin_amdgcn_exp2f(s[j][3]);                        \
                rs += (p0 + p1) + (p2 + p3);                                             \
                bf16x4 pk;                                                               \
                pk[0] = (bf16)p0; pk[1] = (bf16)p1;                                      \
                pk[2] = (bf16)p2; pk[3] = (bf16)p3;                                      \
                *(bf16x4*)(sPt + c15 * 72 + j * 16 + kq * 4) = pk;                       \
            }                                                                            \
            l_s[t] += rs;                                                                \
        }                                                                                \
        bf16x8 pf[2][2];                                                                 \
        _Pragma("unroll") for (int t = 0; t < 2; ++t) {                                  \
            bf16* sPt = (t == 0) ? sP0 : sP1;                                            \
            pf[t][0] = *(const bf16x8*)(sPt + c15 * 72 + kq * 8);                        \
            pf[t][1] = *(const bf16x8*)(sPt + c15 * 72 + 32 + kq * 8);                   \
        }                                                                                \
        _Pragma("unroll") for (int i = 0; i < 4; ++i) {                                  \
            const bf16x8 v0 =                                                            \
                *(const bf16x8*)(sVc + (i * 16 + c15) * 64 + ((kq ^ c7) * 8));           \
            const bf16x8 v1 =                                                            \
                *(const bf16x8*)(sVc + (i * 16 + c15) * 64 + (((4 | kq) ^ c7) * 8));     \
            oacc[0][i] = MFMA(v0, pf[0][0], oacc[0][i]);                                 \
            oacc[0][i] = MFMA(v1, pf[0][1], oacc[0][i]);                                 \
            oacc[1][i] = MFMA(v0, pf[1][0], oacc[1][i]);                                 \
            oacc[1][i] = MFMA(v1, pf[1][1], oacc[1][i]);                                 \
        }                                                                                \
    }

    ATTN_ISSUE(0, 0);
    for (int kv0 = 0; kv0 < 2048; kv0 += 128) {
        __syncthreads();                       // tile kv0 (buf0) ready
        if (kv0 + 64 < 2048) ATTN_ISSUE(kv0 + 64, 1);
        ATTN_COMPUTE(0);
        __syncthreads();                       // tile kv0+64 (buf1) ready
        if (kv0 + 128 < 2048) ATTN_ISSUE(kv0 + 128, 0);
        ATTN_COMPUTE(1);
    }
#undef ATTN_ISSUE
#undef ATTN_COMPUTE

    // final cross-lane denom reduction (2 shuffles per q-tile, once)
#pragma unroll
    for (int t = 0; t < 2; ++t) {
        float rs = l_s[t];
        rs += __shfl_xor(rs, 16, 64);
        rs += __shfl_xor(rs, 32, 64);
        const float linv = 1.0f / rs;
        const long tok = (long)(b * 2048 + q0 + wave * 32 + t * 16 + c15);
#pragma unroll
        for (int i = 0; i < 4; ++i) {
            bf16x4 ov;
#pragma unroll
            for (int r = 0; r < 4; ++r) ov[r] = (bf16)(oacc[t][i][r] * linv);
            *(bf16x4*)(o + tok * 1024 + h * 64 + i * 16 + kq * 4) = ov;
        }
    }
}

// ---------------------------------------------------------------------------
extern "C" void kernel_launch(void* const* d_in, const int* in_sizes, int n_in,
                              void* d_out, int out_size, void* d_ws, size_t ws_size,
                              hipStream_t stream) {
    const float* x      = (const float*)d_in[0];
    const float* ln1_g  = (const float*)d_in[1];
    const float* ln1_b  = (const float*)d_in[2];
    const float* qkv_w  = (const float*)d_in[3];
    const float* proj_w = (const float*)d_in[4];
    const float* proj_b = (const float*)d_in[5];
    const float* ln2_g  = (const float*)d_in[6];
    const float* ln2_b  = (const float*)d_in[7];
    const float* fc1_w  = (const float*)d_in[8];
    const float* fc1_b  = (const float*)d_in[9];
    const float* fc2_w  = (const float*)d_in[10];
    const float* fc2_b  = (const float*)d_in[11];
    float* out = (float*)d_out;

    char* ws = (char*)d_ws;
    bf16* actbuf = (bf16*)(ws);                            // 16 MiB (h / o / h2)
    bf16* wqkv   = (bf16*)(ws + (16ull << 20));            // 6 MiB
    bf16* wproj  = (bf16*)(ws + (22ull << 20));            // 2 MiB
    bf16* wfc1   = (bf16*)(ws + (24ull << 20));            // 8 MiB
    bf16* wfc2   = (bf16*)(ws + (32ull << 20));            // 8 MiB
    bf16* qkvbuf = (bf16*)(ws + (40ull << 20));            // 48 MiB (V region unused)
    bf16* vtbuf  = (bf16*)(ws + (88ull << 20));            // 16 MiB
    bf16* gbuf   = (bf16*)(ws + (40ull << 20));            // 64 MiB (aliases qkv+vt)

    const dim3 blk(256);

    cast4_kernel<<<6144, blk, 0, stream>>>(qkv_w, proj_w, fc1_w, fc2_w,
                                           wqkv, wproj, wfc1, wfc2);

    ln_kernel<<<8192, blk, 0, stream>>>(x, ln1_g, ln1_b, actbuf);

    gemm_bt<3><<<dim3(24, 64), blk, 0, stream>>>(actbuf, wqkv, nullptr, nullptr,
                                                 qkvbuf, vtbuf, 8192, 3072, 1024);
    attn_kernel<<<dim3(64, 16), blk, 0, stream>>>(qkvbuf, vtbuf, actbuf);

    gemm_bt<1><<<dim3(8, 64), blk, 0, stream>>>(actbuf, wproj, proj_b, x,
                                                d_out, nullptr, 8192, 1024, 1024);

    ln_kernel<<<8192, blk, 0, stream>>>(out, ln2_g, ln2_b, actbuf);

    gemm_bt<2><<<dim3(32, 64), blk, 0, stream>>>(actbuf, wfc1, fc1_b, nullptr,
                                                 gbuf, nullptr, 8192, 4096, 1024);
    gemm_bt<1><<<dim3(8, 64), blk, 0, stream>>>(gbuf, wfc2, fc2_b, out,
                                                d_out, nullptr, 8192, 1024, 4096);
}

// Round 6
// 478.083 us; speedup vs baseline: 1.0655x; 1.0655x over previous
//
#include <hip/hip_runtime.h>
#include <math.h>

typedef __bf16 bf16;
typedef __attribute__((ext_vector_type(8))) __bf16 bf16x8;
typedef __attribute__((ext_vector_type(4))) __bf16 bf16x4;
typedef __attribute__((ext_vector_type(4))) float floatx4;

#define MFMA(a, b, c) __builtin_amdgcn_mfma_f32_16x16x32_bf16((a), (b), (c), 0, 0, 0)

__device__ __forceinline__ void async_load16(const bf16* g, bf16* l) {
    __builtin_amdgcn_global_load_lds((const __attribute__((address_space(1))) void*)(g),
                                     (__attribute__((address_space(3))) void*)(l), 16, 0, 0);
}

// fast GELU (tanh form, exp2-based). |diff vs exact erf-gelu| <= ~3e-3.
__device__ __forceinline__ float gelu_fast(float t) {
    const float g  = 0.7978845608f * (t + 0.044715f * t * t * t);
    const float u  = __builtin_amdgcn_exp2f(g * 2.885390082f);  // e^{2g}
    const float th = (u - 1.0f) * __builtin_amdgcn_rcpf(u + 1.0f);
    return 0.5f * t * (1.0f + th);
}

// ---------------------------------------------------------------------------
// fp32 -> bf16 cast of all 4 weight matrices in one launch.
// ---------------------------------------------------------------------------
__global__ __launch_bounds__(256) void cast4_kernel(const float* __restrict__ a0,
                                                    const float* __restrict__ a1,
                                                    const float* __restrict__ a2,
                                                    const float* __restrict__ a3,
                                                    bf16* __restrict__ o0,
                                                    bf16* __restrict__ o1,
                                                    bf16* __restrict__ o2,
                                                    bf16* __restrict__ o3) {
    long i = (long)blockIdx.x * 256 + threadIdx.x;  // 8-elem units
    const float* in;
    bf16* out;
    long off;
    if (i < 393216) { in = a0; out = o0; off = i; }
    else if (i < 524288) { in = a1; out = o1; off = i - 393216; }
    else if (i < 1048576) { in = a2; out = o2; off = i - 524288; }
    else { in = a3; out = o3; off = i - 1048576; }
    const float4 a = ((const float4*)in)[2 * off];
    const float4 b = ((const float4*)in)[2 * off + 1];
    bf16x8 o;
    o[0] = (bf16)a.x; o[1] = (bf16)a.y; o[2] = (bf16)a.z; o[3] = (bf16)a.w;
    o[4] = (bf16)b.x; o[5] = (bf16)b.y; o[6] = (bf16)b.z; o[7] = (bf16)b.w;
    *(bf16x8*)(out + off * 8) = o;
}

// ---------------------------------------------------------------------------
// LayerNorm over 1024 cols, fp32 in -> bf16 out. One block (256 thr) per row.
// ---------------------------------------------------------------------------
__global__ __launch_bounds__(256) void ln_kernel(const float* __restrict__ x,
                                                 const float* __restrict__ g,
                                                 const float* __restrict__ b,
                                                 bf16* __restrict__ out) {
    const int row = blockIdx.x;
    const int tid = threadIdx.x;
    const float4 v = ((const float4*)(x + (long)row * 1024))[tid];
    float s  = v.x + v.y + v.z + v.w;
    float s2 = v.x * v.x + v.y * v.y + v.z * v.z + v.w * v.w;
#pragma unroll
    for (int off = 32; off > 0; off >>= 1) {
        s  += __shfl_xor(s, off, 64);
        s2 += __shfl_xor(s2, off, 64);
    }
    __shared__ float red[8];
    const int wave = tid >> 6, lane = tid & 63;
    if (lane == 0) { red[wave] = s; red[wave + 4] = s2; }
    __syncthreads();
    const float ts  = red[0] + red[1] + red[2] + red[3];
    const float ts2 = red[4] + red[5] + red[6] + red[7];
    const float mu   = ts * (1.0f / 1024.0f);
    const float rstd = rsqrtf(ts2 * (1.0f / 1024.0f) - mu * mu + 1e-5f);
    const float4 gg = ((const float4*)g)[tid];
    const float4 bb = ((const float4*)b)[tid];
    bf16x4 o;
    o[0] = (bf16)((v.x - mu) * rstd * gg.x + bb.x);
    o[1] = (bf16)((v.y - mu) * rstd * gg.y + bb.y);
    o[2] = (bf16)((v.z - mu) * rstd * gg.z + bb.z);
    o[3] = (bf16)((v.w - mu) * rstd * gg.w + bb.w);
    *(bf16x4*)(out + (long)row * 1024 + tid * 4) = o;
}

// ---------------------------------------------------------------------------
// bf16 NT GEMM: C[m,n] = sum_k A[m,k] * B[n,k]  (A:[M,K], B:[N,K] row-major)
// 128x128 tile, BK=64, global_load_lds(16B) staging, XOR chunk swizzle,
// 16x16x32 bf16 MFMA. launch_bounds(256,4): VGPR<=128 -> 4 blocks/CU
// (LDS 32KB allows 5); more resident waves shorten the barrier drain (m114).
// EPI: 0 = bf16 out; 1 = +bias+resid -> fp32; 2 = +bias,GELU -> bf16;
//      3 = qkv: Q/K bf16 out, V cols (n>=2048) stored TRANSPOSED into vtout.
// ---------------------------------------------------------------------------
template <int EPI>
__global__ __launch_bounds__(256, 4)
void gemm_bt(const bf16* __restrict__ A, const bf16* __restrict__ B,
             const float* __restrict__ bias, const float* __restrict__ resid,
             void* __restrict__ Cout, bf16* __restrict__ vtout, int M, int N, int K) {
    __shared__ __align__(16) bf16 sA[128 * 64];
    __shared__ __align__(16) bf16 sB[128 * 64];
    const int tid  = threadIdx.x;
    const int lane = tid & 63;
    const int wave = tid >> 6;
    const int wm = (wave >> 1) << 6;
    const int wn = (wave & 1) << 6;
    const int c15 = lane & 15;
    const int kq  = lane >> 4;
    const int c7  = lane & 7;
    const long tileM = (long)blockIdx.y * 128;
    const long tileN = (long)blockIdx.x * 128;

    floatx4 acc[4][4] = {};

    const int srow = tid >> 3;
    const int scol = ((tid & 7) ^ (srow & 7)) * 8;
    const bf16* Abase = A + (tileM + srow) * (long)K + scol;
    const bf16* Bbase = B + (tileN + srow) * (long)K + scol;
    bf16* sAw = sA + tid * 8;
    bf16* sBw = sB + tid * 8;

    for (int k0 = 0; k0 < K; k0 += 64) {
        __syncthreads();
#pragma unroll
        for (int it = 0; it < 4; ++it) {
            async_load16(Abase + (long)it * 32 * K + k0, sAw + it * 2048);
            async_load16(Bbase + (long)it * 32 * K + k0, sBw + it * 2048);
        }
        __syncthreads();
#pragma unroll
        for (int kk = 0; kk < 2; ++kk) {
            bf16x8 a[4], b[4];
#pragma unroll
            for (int i = 0; i < 4; ++i) {
                const int ch = ((kk << 2) + kq) ^ c7;
                a[i] = *(const bf16x8*)(sA + (wm + i * 16 + c15) * 64 + ch * 8);
                b[i] = *(const bf16x8*)(sB + (wn + i * 16 + c15) * 64 + ch * 8);
            }
#pragma unroll
            for (int i = 0; i < 4; ++i)
#pragma unroll
                for (int j = 0; j < 4; ++j)
                    acc[i][j] = MFMA(a[i], b[j], acc[i][j]);
        }
    }

#pragma unroll
    for (int i = 0; i < 4; ++i)
#pragma unroll
        for (int j = 0; j < 4; ++j) {
            if (EPI == 3 && tileN >= 2048) {
                // V: transposed store. Lane holds 4 consecutive tokens, fixed col.
                const long gnv  = tileN - 2048 + wn + j * 16 + c15;   // b-local V col
                const long tokb = tileM + wm + i * 16 + kq * 4;       // global token base
                const long row  = ((tokb >> 11) << 10) + gnv;         // b*1024 + gnv
                bf16x4 ov;
#pragma unroll
                for (int r = 0; r < 4; ++r) ov[r] = (bf16)acc[i][j][r];
                *(bf16x4*)(vtout + row * 2048 + (tokb & 2047)) = ov;
            } else {
#pragma unroll
                for (int r = 0; r < 4; ++r) {
                    const long gm = tileM + wm + i * 16 + kq * 4 + r;
                    const long gn = tileN + wn + j * 16 + c15;
                    const float v = acc[i][j][r];
                    if (EPI == 0 || EPI == 3) {
                        ((bf16*)Cout)[gm * N + gn] = (bf16)v;
                    } else if (EPI == 1) {
                        ((float*)Cout)[gm * N + gn] = v + bias[gn] + resid[gm * N + gn];
                    } else {
                        ((bf16*)Cout)[gm * N + gn] = (bf16)gelu_fast(v + bias[gn]);
                    }
                }
            }
        }
}

// ---------------------------------------------------------------------------
// Flash attention, S^T/O^T formulation, NO online max (scores bounded; see R3).
// R4 structure restored: single-buffer sK/sV (R5 dbuf cost occupancy for no
// overlap gain — m99/m100 pattern), launch_bounds(256,4), 34.8KB LDS.
// Block = 256 thr (4 waves), 128 q rows per block (wave: 32 q = 2 q-tiles).
// S^T = K.Q^T; scale*log2(e) folded into Q; p = exp2(S). O^T = V^T.P^T.
// Grid: x = bh (64) -> same-bh blocks land on same XCD; K/V L2-resident.
// ---------------------------------------------------------------------------
__global__ __launch_bounds__(256, 4)
void attn_kernel(const bf16* __restrict__ qkv, const bf16* __restrict__ vt,
                 bf16* __restrict__ o) {
    __shared__ __align__(16) bf16 sK[64 * 64];
    __shared__ __align__(16) bf16 sV[64 * 64];          // vt tile: [d][kv]
    __shared__ __align__(16) bf16 sP[8][16 * 72];       // [wave*2+t][q][kv(+pad)]
    const int bh = blockIdx.x, b = bh >> 4, h = bh & 15;
    const int q0 = blockIdx.y * 128;
    const int tid = threadIdx.x, lane = tid & 63, wave = tid >> 6;
    const int c15 = lane & 15, kq = lane >> 4, c7 = lane & 7;

    // Q fragments (B-operand layout: n=c15, k=kq*8..+8), pre-scaled by log2(e)/8
    bf16x8 qf[2][2];
#pragma unroll
    for (int t = 0; t < 2; ++t) {
        const bf16* qrow =
            qkv + ((long)(b * 2048 + q0 + wave * 32 + t * 16 + c15)) * 3072 + h * 64;
#pragma unroll
        for (int kk = 0; kk < 2; ++kk) {
            const bf16x8 raw = *(const bf16x8*)(qrow + kk * 32 + kq * 8);
            bf16x8 sc;
#pragma unroll
            for (int e = 0; e < 8; ++e) sc[e] = (bf16)((float)raw[e] * 0.18033688f);
            qf[t][kk] = sc;
        }
    }

    floatx4 oacc[2][4] = {};
    float l_s[2] = {0.f, 0.f};

    const bf16* kbase = qkv + ((long)b * 2048) * 3072 + 1024 + h * 64;
    const bf16* vbase = vt + (long)bh * 64 * 2048;

    const int srow = tid >> 3;
    const int scol = ((tid & 7) ^ (srow & 7)) * 8;
    bf16* sKw = sK + tid * 8;
    bf16* sVw = sV + tid * 8;
    bf16* sP0 = sP[wave * 2];
    bf16* sP1 = sP[wave * 2 + 1];

    for (int kv0 = 0; kv0 < 2048; kv0 += 64) {
        __syncthreads();
#pragma unroll
        for (int it = 0; it < 2; ++it) {
            async_load16(kbase + (long)(kv0 + it * 32 + srow) * 3072 + scol, sKw + it * 2048);
            async_load16(vbase + (long)(it * 32 + srow) * 2048 + kv0 + scol, sVw + it * 2048);
        }
        __syncthreads();

        // S^T: s[t][j][r] = log2e * score(kv = j*16 + kq*4 + r, q = c15)
        floatx4 s0[4], s1[4];
#pragma unroll
        for (int j = 0; j < 4; ++j) {
            const bf16x8 k0 = *(const bf16x8*)(sK + (j * 16 + c15) * 64 + ((kq ^ c7) * 8));
            const bf16x8 k1 = *(const bf16x8*)(sK + (j * 16 + c15) * 64 + (((4 | kq) ^ c7) * 8));
            floatx4 a0 = {0.f, 0.f, 0.f, 0.f}, a1 = {0.f, 0.f, 0.f, 0.f};
            a0 = MFMA(k0, qf[0][0], a0);
            a0 = MFMA(k1, qf[0][1], a0);
            a1 = MFMA(k0, qf[1][0], a1);
            a1 = MFMA(k1, qf[1][1], a1);
            s0[j] = a0;
            s1[j] = a1;
        }

        // p = exp2(s); accumulate per-lane denom; write P^T rows (contig kv/lane)
#pragma unroll
        for (int t = 0; t < 2; ++t) {
            floatx4* s = (t == 0) ? s0 : s1;
            bf16* sPt = (t == 0) ? sP0 : sP1;
            float rs = 0.f;
#pragma unroll
            for (int j = 0; j < 4; ++j) {
                const float p0 = __builtin_amdgcn_exp2f(s[j][0]);
                const float p1 = __builtin_amdgcn_exp2f(s[j][1]);
                const float p2 = __builtin_amdgcn_exp2f(s[j][2]);
                const float p3 = __builtin_amdgcn_exp2f(s[j][3]);
                rs += (p0 + p1) + (p2 + p3);
                bf16x4 pk;
                pk[0] = (bf16)p0; pk[1] = (bf16)p1; pk[2] = (bf16)p2; pk[3] = (bf16)p3;
                *(bf16x4*)(sPt + c15 * 72 + j * 16 + kq * 4) = pk;
            }
            l_s[t] += rs;
        }

        // PV: O^T += V^T . P^T
        bf16x8 pf[2][2];
#pragma unroll
        for (int t = 0; t < 2; ++t) {
            bf16* sPt = (t == 0) ? sP0 : sP1;
            pf[t][0] = *(const bf16x8*)(sPt + c15 * 72 + kq * 8);
            pf[t][1] = *(const bf16x8*)(sPt + c15 * 72 + 32 + kq * 8);
        }
#pragma unroll
        for (int i = 0; i < 4; ++i) {
            const bf16x8 v0 = *(const bf16x8*)(sV + (i * 16 + c15) * 64 + ((kq ^ c7) * 8));
            const bf16x8 v1 = *(const bf16x8*)(sV + (i * 16 + c15) * 64 + (((4 | kq) ^ c7) * 8));
            oacc[0][i] = MFMA(v0, pf[0][0], oacc[0][i]);
            oacc[0][i] = MFMA(v1, pf[0][1], oacc[0][i]);
            oacc[1][i] = MFMA(v0, pf[1][0], oacc[1][i]);
            oacc[1][i] = MFMA(v1, pf[1][1], oacc[1][i]);
        }
    }

    // final cross-lane denom reduction (2 shuffles per q-tile, once)
#pragma unroll
    for (int t = 0; t < 2; ++t) {
        float rs = l_s[t];
        rs += __shfl_xor(rs, 16, 64);
        rs += __shfl_xor(rs, 32, 64);
        const float linv = 1.0f / rs;
        const long tok = (long)(b * 2048 + q0 + wave * 32 + t * 16 + c15);
#pragma unroll
        for (int i = 0; i < 4; ++i) {
            bf16x4 ov;
#pragma unroll
            for (int r = 0; r < 4; ++r) ov[r] = (bf16)(oacc[t][i][r] * linv);
            *(bf16x4*)(o + tok * 1024 + h * 64 + i * 16 + kq * 4) = ov;
        }
    }
}

// ---------------------------------------------------------------------------
extern "C" void kernel_launch(void* const* d_in, const int* in_sizes, int n_in,
                              void* d_out, int out_size, void* d_ws, size_t ws_size,
                              hipStream_t stream) {
    const float* x      = (const float*)d_in[0];
    const float* ln1_g  = (const float*)d_in[1];
    const float* ln1_b  = (const float*)d_in[2];
    const float* qkv_w  = (const float*)d_in[3];
    const float* proj_w = (const float*)d_in[4];
    const float* proj_b = (const float*)d_in[5];
    const float* ln2_g  = (const float*)d_in[6];
    const float* ln2_b  = (const float*)d_in[7];
    const float* fc1_w  = (const float*)d_in[8];
    const float* fc1_b  = (const float*)d_in[9];
    const float* fc2_w  = (const float*)d_in[10];
    const float* fc2_b  = (const float*)d_in[11];
    float* out = (float*)d_out;

    char* ws = (char*)d_ws;
    bf16* actbuf = (bf16*)(ws);                            // 16 MiB (h / o / h2)
    bf16* wqkv   = (bf16*)(ws + (16ull << 20));            // 6 MiB
    bf16* wproj  = (bf16*)(ws + (22ull << 20));            // 2 MiB
    bf16* wfc1   = (bf16*)(ws + (24ull << 20));            // 8 MiB
    bf16* wfc2   = (bf16*)(ws + (32ull << 20));            // 8 MiB
    bf16* qkvbuf = (bf16*)(ws + (40ull << 20));            // 48 MiB (V region unused)
    bf16* vtbuf  = (bf16*)(ws + (88ull << 20));            // 16 MiB
    bf16* gbuf   = (bf16*)(ws + (40ull << 20));            // 64 MiB (aliases qkv+vt)

    const dim3 blk(256);

    cast4_kernel<<<6144, blk, 0, stream>>>(qkv_w, proj_w, fc1_w, fc2_w,
                                           wqkv, wproj, wfc1, wfc2);

    ln_kernel<<<8192, blk, 0, stream>>>(x, ln1_g, ln1_b, actbuf);

    gemm_bt<3><<<dim3(24, 64), blk, 0, stream>>>(actbuf, wqkv, nullptr, nullptr,
                                                 qkvbuf, vtbuf, 8192, 3072, 1024);
    attn_kernel<<<dim3(64, 16), blk, 0, stream>>>(qkvbuf, vtbuf, actbuf);

    gemm_bt<1><<<dim3(8, 64), blk, 0, stream>>>(actbuf, wproj, proj_b, x,
                                                d_out, nullptr, 8192, 1024, 1024);

    ln_kernel<<<8192, blk, 0, stream>>>(out, ln2_g, ln2_b, actbuf);

    gemm_bt<2><<<dim3(32, 64), blk, 0, stream>>>(actbuf, wfc1, fc1_b, nullptr,
                                                 gbuf, nullptr, 8192, 4096, 1024);
    gemm_bt<1><<<dim3(8, 64), blk, 0, stream>>>(gbuf, wfc2, fc2_b, out,
                                                d_out, nullptr, 8192, 1024, 4096);
}